// Round 13
// baseline (324.832 us; speedup 1.0000x reference)
//
#include <hip/hip_runtime.h>
#include <cstdint>
#include <cstddef>

typedef unsigned short u16;
typedef __attribute__((ext_vector_type(8))) __bf16 bf16x8;
typedef __attribute__((ext_vector_type(4))) unsigned short u16x4;
typedef __attribute__((ext_vector_type(8))) unsigned short u16x8;
typedef __attribute__((ext_vector_type(4))) float f32x4;

#define NTOK 197
#define TT   209
#define CDIM 768
#define NH   12
#define HD   64
#define BATCH 64
#define GM (BATCH*TT)   // 13376
#define VTP 224         // padded T stride for transposed V

__device__ __forceinline__ float bf2f(u16 u){ return __uint_as_float(((unsigned)u)<<16); }
__device__ __forceinline__ u16 f2bf(float f){
  unsigned x = __float_as_uint(f);
  return (u16)((x + 0x7FFFu + ((x>>16)&1u)) >> 16);   // RNE; inputs finite
}

__device__ __forceinline__ void gll16(const void* g, void* l){
  __builtin_amdgcn_global_load_lds((const __attribute__((address_space(1))) void*)g,
                                   (__attribute__((address_space(3))) void*)l,
                                   16, 0, 0);
}

__device__ __forceinline__ float wsum64(float v){
  #pragma unroll
  for (int o = 32; o > 0; o >>= 1) v += __shfl_xor(v, o, 64);
  return v;
}

// ---------------------------------------------------------------- dtype detect
__global__ __launch_bounds__(64) void detect_kernel(const u16* __restrict__ x, int* flag){
  const int lane = threadIdx.x;
  float mx = 0.f;
  #pragma unroll
  for (int i = 0; i < 16; i++) {
    float v = fabsf(bf2f(x[i*64 + lane]));
    if (!(v < 1e30f)) v = 1e30f;
    mx = fmaxf(mx, v);
  }
  #pragma unroll
  for (int o = 32; o; o >>= 1) mx = fmaxf(mx, __shfl_xor(mx, o, 64));
  if (lane == 0) *flag = (mx < 1e5f) ? 1 : 0;   // 1 = device buffers are bf16
}

// ---------------------------------------------------------------- fused convert
struct CA { const void* in[10]; void* out[10]; int n[10]; };
__global__ __launch_bounds__(256) void convert_all_kernel(CA a, const int* __restrict__ flag){
  const int seg = blockIdx.y;
  if (seg == 1 || seg == 3) return;
  const int f = *flag;
  if (seg == 0 && f) return;
  const int n = a.n[seg];
  const int n4 = n >> 2;
  u16* out = (u16*)a.out[seg];
  if (f) {
    const u16x4* in = (const u16x4*)a.in[seg];
    for (int i = blockIdx.x*256 + threadIdx.x; i < n4; i += gridDim.x*256)
      ((u16x4*)out)[i] = in[i];
  } else {
    const f32x4* in = (const f32x4*)a.in[seg];
    for (int i = blockIdx.x*256 + threadIdx.x; i < n4; i += gridDim.x*256){
      f32x4 v = in[i];
      u16x4 o;
      #pragma unroll
      for (int j=0;j<4;j++) o[j] = f2bf(v[j]);
      ((u16x4*)out)[i] = o;
    }
  }
  if (blockIdx.x == 0 && (int)threadIdx.x < (n & 3)) {
    int i = (n4 << 2) + threadIdx.x;
    out[i] = f ? ((const u16*)a.in[seg])[i] : f2bf(((const float*)a.in[seg])[i]);
  }
}

// ---------------------------------------------------------------- transpose (+convert)
__global__ __launch_bounds__(256) void transpose_kernel(
    const void* __restrict__ in, u16* __restrict__ out, int K, int N,
    const int* __restrict__ flag)
{
  __shared__ u16 lds[64][66];
  const int f = *flag;
  const int n0 = blockIdx.x*64, k0 = blockIdx.y*64;
  const int c = threadIdx.x & 63, r0 = threadIdx.x >> 6;
  #pragma unroll
  for (int i=0;i<16;i++) {
    int r = i*4 + r0;
    size_t idx = (size_t)(k0+r)*N + n0 + c;
    lds[r][c] = f ? ((const u16*)in)[idx] : f2bf(((const float*)in)[idx]);
  }
  __syncthreads();
  #pragma unroll
  for (int i=0;i<16;i++) {
    int r = i*4 + r0;
    out[(size_t)(n0+r)*K + k0 + c] = lds[c][r];
  }
}

// ---------------------------------------------------------------- head token
__global__ __launch_bounds__(256) void ht_kernel(
    const u16* __restrict__ xc, const void* __restrict__ xr,
    const u16* __restrict__ htw, const u16* __restrict__ htb,
    const u16* __restrict__ lng, const u16* __restrict__ lnb,
    const u16* __restrict__ pos, u16* __restrict__ ht, const int* __restrict__ flag)
{
  const int b = blockIdx.x, half = blockIdx.y;
  const int tid = threadIdx.x;
  __shared__ float part[4][384];
  __shared__ float msh[384];
  const int f = *flag;
  const u16* x = f ? (const u16*)xr : xc;

  const u16* xb = x + (size_t)b*NTOK*CDIM + half*384;
  if (tid < 192) {
    const int s = tid % 48, rg = tid / 48;
    float a[8] = {0.f,0.f,0.f,0.f,0.f,0.f,0.f,0.f};
    for (int n = rg; n < NTOK; n += 4) {
      u16x8 v = *(const u16x8*)&xb[(size_t)n*CDIM + s*8];
      #pragma unroll
      for (int e=0;e<8;e++) a[e] += bf2f(v[e]);
    }
    #pragma unroll
    for (int e=0;e<8;e++) part[rg][s*8+e] = a[e];
  }
  __syncthreads();
  for (int i = tid; i < 384; i += 256)
    msh[i] = (part[0][i]+part[1][i]+part[2][i]+part[3][i]) * (1.0f/(float)NTOK);
  __syncthreads();

  const float gam = bf2f(lng[tid & 63]), bet = bf2f(lnb[tid & 63]);
  #pragma unroll
  for (int hh = 0; hh < 6; hh++) {
    const int h = half*6 + hh;
    float v0 = bf2f(htb[tid]), v1 = bf2f(htb[tid+256]), v2 = bf2f(htb[tid+512]);
    const float* mh = &msh[hh*HD];
    for (int d = 0; d < HD; d++) {
      const float md = mh[d];
      const u16* wr = htw + (size_t)d*CDIM;
      v0 += md * bf2f(wr[tid]);
      v1 += md * bf2f(wr[tid+256]);
      v2 += md * bf2f(wr[tid+512]);
    }
    float vv[3] = {v0, v1, v2};
    #pragma unroll
    for (int ch = 0; ch < 3; ch++) {
      int c = ch*256 + tid;
      float mu = wsum64(vv[ch]) * (1.0f/(float)HD);
      float dv = vv[ch] - mu;
      float var = wsum64(dv*dv) * (1.0f/(float)HD);
      float y = dv * rsqrtf(var + 1e-5f) * gam + bet;
      float ge = 0.5f * y * (1.0f + erff(y * 0.70710678118654752f));
      float o = ge + bf2f(pos[h*CDIM + c]);
      ht[((size_t)(b*NH + h))*CDIM + c] = f2bf(o);
    }
  }
}

// ---------------------------------------------------------------- GEMM (1-wave, barrier-free)
// One wave per block, 64x64 tile, BK=32. Wave-private LDS (2 buf x 8KB),
// gll16 staging, depth-1 prefetch, counted vmcnt(8). ZERO barriers: the sync
// domain is a single wave, so ordering is by program order + vmcnt only:
//  - reads of buf[cb] at iter kt are gated by vmcnt(8) ensuring stage(kt) landed;
//  - WAR: iter kt-1's ds_reads execute at issue, strictly before iter kt's
//    gll16 writes to the same buffer are issued.
// 10 blocks/CU (LDS 160/16) = 10 independent pipelines per CU.
// Both-sides XOR seg swizzle (R5-proven) + m204 bijective XCD remap.
template<int MODE>
__global__ __launch_bounds__(64, 3) void gemm_kernel(
    const u16* __restrict__ A0c, const void* __restrict__ A0r,
    const u16* __restrict__ A1,
    const u16* __restrict__ Bt, const u16* __restrict__ bias,
    u16* __restrict__ qo, u16* __restrict__ ko, u16* __restrict__ vo,
    void* __restrict__ outv, float* __restrict__ csb, const int* __restrict__ flag)
{
  const int lane = threadIdx.x;
  const int lr = lane & 15, kg = lane >> 4;

  // m204 bijective XCD remap; tm = wg/NT -> A-panel blocks contiguous per XCD
  const int NT = gridDim.x;
  const int nwg = NT * gridDim.y;
  const int orig = blockIdx.y * NT + blockIdx.x;
  const int xcd = orig & 7, sIdx = orig >> 3;
  const int q = nwg >> 3, r = nwg & 7;
  const int wg = ((xcd < r) ? xcd*(q+1) : r*(q+1) + (xcd-r)*q) + sIdx;
  const int tm = wg / NT, tn = wg - tm*NT;

  __shared__ __align__(16) u16 As[2][2048];   // [buf][row*32 + seg*8 + e], 4KB
  __shared__ __align__(16) u16 Bs[2][2048];

  const int f = *flag;
  const u16* A0 = (MODE == 0) ? (f ? (const u16*)A0r : A0c) : A0c;

  f32x4 acc[4][4];
  #pragma unroll
  for (int i=0;i<4;i++)
    #pragma unroll
    for (int j=0;j<4;j++) acc[i][j] = (f32x4){0.f,0.f,0.f,0.f};

  // staging: gll16 i covers tile rows i*16 + (lane>>2); source seg XOR-swizzled
  // within the row's 64B chunk (line-coalesced).
  const u16* garow[4];
  const u16* gbrow[4];
  #pragma unroll
  for (int i=0;i<4;i++){
    int row = i*16 + (lane >> 2);
    int rr = tm*64 + row; if (rr > GM-1) rr = GM-1;
    if (MODE == 0) {
      int bb = rr / TT; int t = rr - bb*TT;
      garow[i] = (t < NTOK) ? (A0 + (size_t)(bb*NTOK + t)*CDIM)
                            : (A1 + (size_t)(bb*NH + (t - NTOK))*CDIM);
    } else {
      garow[i] = A0 + (size_t)rr*CDIM;
    }
    gbrow[i] = Bt + (size_t)(tn*64 + row)*CDIM;
  }
  const int gseg = (lane & 3) ^ ((lane >> 3) & 3);   // = seg ^ ((row>>1)&3)

#define STAGE(kt_, bf_) do { \
    const int ko_ = (kt_)*32 + gseg*8; \
    gll16(garow[0] + ko_, (void*)&As[bf_][0*512]); \
    gll16(garow[1] + ko_, (void*)&As[bf_][1*512]); \
    gll16(garow[2] + ko_, (void*)&As[bf_][2*512]); \
    gll16(garow[3] + ko_, (void*)&As[bf_][3*512]); \
    gll16(gbrow[0] + ko_, (void*)&Bs[bf_][0*512]); \
    gll16(gbrow[1] + ko_, (void*)&Bs[bf_][1*512]); \
    gll16(gbrow[2] + ko_, (void*)&Bs[bf_][2*512]); \
    gll16(gbrow[3] + ko_, (void*)&Bs[bf_][3*512]); \
  } while(0)

  STAGE(0, 0);

  const int spA = kg ^ ((lr >> 1) & 3);   // read-side swizzled segment

  #pragma unroll
  for (int kt = 0; kt < 24; kt++) {
    const int cb = kt & 1;
    if (kt < 23) {
      STAGE(kt+1, (kt+1)&1);
      asm volatile("s_waitcnt vmcnt(8)" ::: "memory");   // stage kt fully landed
    } else {
      asm volatile("s_waitcnt vmcnt(0)" ::: "memory");
    }
    // no barrier: single-wave sync domain

    bf16x8 av[4], bv[4];
    #pragma unroll
    for (int mi=0; mi<4; mi++)
      av[mi] = *(const bf16x8*)&As[cb][(mi*16+lr)*32 + spA*8];
    #pragma unroll
    for (int ni=0; ni<4; ni++)
      bv[ni] = *(const bf16x8*)&Bs[cb][(ni*16+lr)*32 + spA*8];
    #pragma unroll
    for (int mi=0; mi<4; mi++)
      #pragma unroll
      for (int ni=0; ni<4; ni++)
        acc[mi][ni] = __builtin_amdgcn_mfma_f32_16x16x32_bf16(av[mi], bv[ni], acc[mi][ni], 0,0,0);
  }
#undef STAGE

  #pragma unroll
  for (int mi=0; mi<4; mi++){
    const int rb = tm*64 + mi*16 + kg*4;
    #pragma unroll
    for (int ni=0; ni<4; ni++){
      const int c = tn*64 + ni*16 + lr;
      const float bs = bf2f(bias[c]);
      if (MODE == 0) {
        const int which = (c >= 2*CDIM) ? 2 : (c >= CDIM ? 1 : 0);
        const int hh = (c - which*CDIM) >> 6;
        const int dd = c & 63;
        #pragma unroll
        for (int j=0;j<4;j++){
          int rr = rb + j;
          if (rr < GM) {
            int bb = rr / TT; int t = rr - bb*TT;
            u16 res = f2bf(acc[mi][ni][j] + bs);
            if (which == 2)      vo[((size_t)(bb*NH + hh)*HD + dd)*VTP + t] = res;
            else if (which == 1) ko[((size_t)(bb*NH + hh)*TT + t)*HD + dd] = res;
            else                 qo[((size_t)(bb*NH + hh)*TT + t)*HD + dd] = res;
          }
        }
      } else {
        #pragma unroll
        for (int j=0;j<4;j++){
          int rr = rb + j;
          if (rr < GM) {
            int bb = rr / TT; int t = rr - bb*TT;
            float v = acc[mi][ni][j] + bs;
            if (t >= 1 && t < NTOK) {
              size_t oi = ((size_t)(bb*NTOK + t))*CDIM + c;
              if (f) ((u16*)outv)[oi] = f2bf(v);
              else   ((float*)outv)[oi] = v;
            } else {
              int idx = (t == 0) ? 0 : (t - NTOK + 1);   // 0, 1..12
              csb[((size_t)(bb*13 + idx))*CDIM + c] = v;
            }
          }
        }
      }
    }
  }
}

// ---------------------------------------------------------------- attention
__global__ __launch_bounds__(256) void attn_kernel(
    const u16* __restrict__ qb, const u16* __restrict__ kb,
    const u16* __restrict__ vt, u16* __restrict__ ob)
{
  __shared__ __align__(16) u16 P[4][7*16*32];   // 28672 B
  const int tid = threadIdx.x;
  const int lane = tid & 63;
  const int w = tid >> 6;
  const int lr = lane & 15, kg = lane >> 4;

  const int cid = blockIdx.x*4 + w;
  const int bh = cid / 14, ck = cid - bh*14;
  const int b = bh / NH, h = bh - b*NH;
  const int q0 = ck*16;

  const u16* qg = qb + (size_t)bh*TT*HD;
  const u16* kgp = kb + (size_t)bh*TT*HD;
  const u16* vg = vt + (size_t)bh*HD*VTP;

  int qrow = q0 + lr; if (qrow > TT-1) qrow = TT-1;
  const bf16x8 qf0 = *(const bf16x8*)&qg[qrow*HD + kg*8];
  const bf16x8 qf1 = *(const bf16x8*)&qg[qrow*HD + 32 + kg*8];

  f32x4 sv[14];
  #pragma unroll
  for (int kt = 0; kt < 14; kt++) {
    int krow = kt*16 + lr; if (krow > TT-1) krow = TT-1;
    const u16* kr = kgp + krow*HD;
    bf16x8 kf0 = *(const bf16x8*)&kr[kg*8];
    bf16x8 kf1 = *(const bf16x8*)&kr[32 + kg*8];
    f32x4 sa = {0.f,0.f,0.f,0.f};
    sa = __builtin_amdgcn_mfma_f32_16x16x32_bf16(kf0, qf0, sa, 0,0,0);
    sa = __builtin_amdgcn_mfma_f32_16x16x32_bf16(kf1, qf1, sa, 0,0,0);
    sv[kt] = sa;
  }

  float m = -3.0e38f;
  #pragma unroll
  for (int kt = 0; kt < 13; kt++)
    #pragma unroll
    for (int j=0;j<4;j++){ sv[kt][j] *= 0.125f; m = fmaxf(m, sv[kt][j]); }
  #pragma unroll
  for (int j=0;j<4;j++){
    sv[13][j] *= 0.125f;
    if (208 + kg*4 + j < TT) m = fmaxf(m, sv[13][j]);
  }
  m = fmaxf(m, __shfl_xor(m, 16, 64));
  m = fmaxf(m, __shfl_xor(m, 32, 64));

  float ssum = 0.f;
  #pragma unroll
  for (int kt = 0; kt < 13; kt++)
    #pragma unroll
    for (int j=0;j<4;j++){ float e = __expf(sv[kt][j] - m); sv[kt][j] = e; ssum += e; }
  #pragma unroll
  for (int j=0;j<4;j++){
    float e = (208 + kg*4 + j < TT) ? __expf(sv[13][j] - m) : 0.f;
    sv[13][j] = e; ssum += e;
  }
  ssum += __shfl_xor(ssum, 16, 64);
  ssum += __shfl_xor(ssum, 32, 64);
  const float inv = 1.0f / ssum;

  u16* Pw = &P[w][0];
  #pragma unroll
  for (int kt = 0; kt < 14; kt++) {
    u16x4 pk;
    #pragma unroll
    for (int j=0;j<4;j++) pk[j] = f2bf(sv[kt][j] * inv);
    *(u16x4*)&Pw[(kt>>1)*512 + lr*32 + (kt&1)*16 + kg*4] = pk;
  }

  f32x4 acc[4];
  #pragma unroll
  for (int dt=0; dt<4; dt++) acc[dt] = (f32x4){0.f,0.f,0.f,0.f};
  #pragma unroll
  for (int ks = 0; ks < 7; ks++) {
    bf16x8 pf = *(const bf16x8*)&Pw[ks*512 + lr*32 + kg*8];
    #pragma unroll
    for (int dt = 0; dt < 4; dt++) {
      bf16x8 vf = *(const bf16x8*)&vg[(dt*16+lr)*VTP + ks*32 + kg*8];
      acc[dt] = __builtin_amdgcn_mfma_f32_16x16x32_bf16(pf, vf, acc[dt], 0,0,0);
    }
  }

  #pragma unroll
  for (int dt = 0; dt < 4; dt++)
    #pragma unroll
    for (int j = 0; j < 4; j++) {
      int tq = q0 + kg*4 + j;
      if (tq < TT)
        ob[((size_t)(b*TT + tq))*CDIM + h*HD + dt*16 + lr] = f2bf(acc[dt][j]);
    }
}

// ---------------------------------------------------------------- final2 (cls row)
__global__ __launch_bounds__(256) void final2_kernel(
    const float* __restrict__ csb, void* __restrict__ outv, const int* __restrict__ flag)
{
  const int f = *flag;
  int i = blockIdx.x*256 + threadIdx.x;
  if (i >= BATCH*CDIM) return;
  int b = i / CDIM, c = i - b*CDIM;
  const float* p = csb + (size_t)b*13*CDIM + c;
  float s = 0.f;
  #pragma unroll
  for (int j = 1; j <= 12; j++) s += p[(size_t)j*CDIM];
  float v = p[0] + s * (1.0f/12.0f);
  size_t oi = ((size_t)b*NTOK)*CDIM + c;
  if (f) ((u16*)outv)[oi] = f2bf(v);
  else   ((float*)outv)[oi] = v;
}

// ---------------------------------------------------------------- launch
extern "C" void kernel_launch(void* const* d_in, const int* in_sizes, int n_in,
                              void* d_out, int out_size, void* d_ws, size_t ws_size,
                              hipStream_t stream)
{
  char* ws = (char*)d_ws;
  size_t off = 0;
  auto alloc = [&](size_t bytes)->void* {
    void* p = ws + off; off += (bytes + 255) & ~(size_t)255; return p;
  };

  int* flag = (int*)alloc(256);

  u16* cin[10];
  for (int i = 0; i < 10; i++) cin[i] = (u16*)alloc((size_t)in_sizes[i]*2);

  u16* qkvT  = (u16*)alloc((size_t)3*CDIM*CDIM*2);        // 2304 x 768
  u16* projT = (u16*)alloc((size_t)CDIM*CDIM*2);          // 768 x 768
  u16* htb_  = (u16*)alloc((size_t)BATCH*NH*CDIM*2);      // (B*H) x 768
  u16* qb    = (u16*)alloc((size_t)BATCH*NH*TT*HD*2);     // (B,H,T,HD)
  u16* kb    = (u16*)alloc((size_t)BATCH*NH*TT*HD*2);
  u16* vb    = (u16*)alloc((size_t)BATCH*NH*HD*VTP*2);    // (B,H,HD,VTP) transposed
  u16* ao    = (u16*)alloc((size_t)GM*CDIM*2);            // (B*T) x 768
  float* csb = (float*)alloc((size_t)BATCH*13*CDIM*4);    // cls side buffer

  detect_kernel<<<1, 64, 0, stream>>>((const u16*)d_in[0], flag);

  CA ca;
  for (int i = 0; i < 10; i++) { ca.in[i] = d_in[i]; ca.out[i] = cin[i]; ca.n[i] = in_sizes[i]; }
  convert_all_kernel<<<dim3(256, 10), 256, 0, stream>>>(ca, flag);

  transpose_kernel<<<dim3(3*CDIM/64, CDIM/64), 256, 0, stream>>>(d_in[1], qkvT, CDIM, 3*CDIM, flag);
  transpose_kernel<<<dim3(CDIM/64,   CDIM/64), 256, 0, stream>>>(d_in[3], projT, CDIM, CDIM, flag);
  ht_kernel<<<dim3(BATCH, 2), 256, 0, stream>>>(cin[0], d_in[0], cin[5], cin[6], cin[7], cin[8], cin[9], htb_, flag);
  gemm_kernel<0><<<dim3(3*CDIM/64, (GM+63)/64), 64, 0, stream>>>(
      cin[0], d_in[0], htb_, qkvT, cin[2], qb, kb, vb, nullptr, nullptr, flag);
  attn_kernel<<<(BATCH*NH*14)/4, 256, 0, stream>>>(qb, kb, vb, ao);
  gemm_kernel<1><<<dim3(CDIM/64, (GM+63)/64), 64, 0, stream>>>(
      ao, nullptr, nullptr, projT, cin[4], nullptr, nullptr, nullptr, d_out, csb, flag);
  final2_kernel<<<(BATCH*CDIM+255)/256, 256, 0, stream>>>(csb, d_out, flag);
}

// Round 14
// 275.826 us; speedup vs baseline: 1.1777x; 1.1777x over previous
//
#include <hip/hip_runtime.h>
#include <cstdint>
#include <cstddef>

typedef unsigned short u16;
typedef __attribute__((ext_vector_type(8))) __bf16 bf16x8;
typedef __attribute__((ext_vector_type(4))) unsigned short u16x4;
typedef __attribute__((ext_vector_type(8))) unsigned short u16x8;
typedef __attribute__((ext_vector_type(4))) float f32x4;

#define NTOK 197
#define TT   209
#define CDIM 768
#define NH   12
#define HD   64
#define BATCH 64
#define GM (BATCH*TT)   // 13376
#define VTP 224         // padded T stride for transposed V
#define NQKV 2304

__device__ __forceinline__ float bf2f(u16 u){ return __uint_as_float(((unsigned)u)<<16); }
__device__ __forceinline__ u16 f2bf(float f){
  unsigned x = __float_as_uint(f);
  return (u16)((x + 0x7FFFu + ((x>>16)&1u)) >> 16);   // RNE; inputs finite
}

__device__ __forceinline__ void gll16(const void* g, void* l){
  __builtin_amdgcn_global_load_lds((const __attribute__((address_space(1))) void*)g,
                                   (__attribute__((address_space(3))) void*)l,
                                   16, 0, 0);
}

__device__ __forceinline__ float wsum64(float v){
  #pragma unroll
  for (int o = 32; o > 0; o >>= 1) v += __shfl_xor(v, o, 64);
  return v;
}

// ---------------------------------------------------------------- dtype detect
__global__ __launch_bounds__(64) void detect_kernel(const u16* __restrict__ x, int* flag){
  const int lane = threadIdx.x;
  float mx = 0.f;
  #pragma unroll
  for (int i = 0; i < 16; i++) {
    float v = fabsf(bf2f(x[i*64 + lane]));
    if (!(v < 1e30f)) v = 1e30f;
    mx = fmaxf(mx, v);
  }
  #pragma unroll
  for (int o = 32; o; o >>= 1) mx = fmaxf(mx, __shfl_xor(mx, o, 64));
  if (lane == 0) *flag = (mx < 1e5f) ? 1 : 0;   // 1 = device buffers are bf16
}

// ---------------------------------------------------------------- fused convert
struct CA { const void* in[10]; void* out[10]; int n[10]; };
__global__ __launch_bounds__(256) void convert_all_kernel(CA a, const int* __restrict__ flag){
  const int seg = blockIdx.y;
  if (seg == 1 || seg == 3) return;
  const int f = *flag;
  if (seg == 0 && f) return;
  const int n = a.n[seg];
  const int n4 = n >> 2;
  u16* out = (u16*)a.out[seg];
  if (f) {
    const u16x4* in = (const u16x4*)a.in[seg];
    for (int i = blockIdx.x*256 + threadIdx.x; i < n4; i += gridDim.x*256)
      ((u16x4*)out)[i] = in[i];
  } else {
    const f32x4* in = (const f32x4*)a.in[seg];
    for (int i = blockIdx.x*256 + threadIdx.x; i < n4; i += gridDim.x*256){
      f32x4 v = in[i];
      u16x4 o;
      #pragma unroll
      for (int j=0;j<4;j++) o[j] = f2bf(v[j]);
      ((u16x4*)out)[i] = o;
    }
  }
  if (blockIdx.x == 0 && (int)threadIdx.x < (n & 3)) {
    int i = (n4 << 2) + threadIdx.x;
    out[i] = f ? ((const u16*)a.in[seg])[i] : f2bf(((const float*)a.in[seg])[i]);
  }
}

// ---------------------------------------------------------------- transpose (+convert)
__global__ __launch_bounds__(256) void transpose_kernel(
    const void* __restrict__ in, u16* __restrict__ out, int K, int N,
    const int* __restrict__ flag)
{
  __shared__ u16 lds[64][66];
  const int f = *flag;
  const int n0 = blockIdx.x*64, k0 = blockIdx.y*64;
  const int c = threadIdx.x & 63, r0 = threadIdx.x >> 6;
  #pragma unroll
  for (int i=0;i<16;i++) {
    int r = i*4 + r0;
    size_t idx = (size_t)(k0+r)*N + n0 + c;
    lds[r][c] = f ? ((const u16*)in)[idx] : f2bf(((const float*)in)[idx]);
  }
  __syncthreads();
  #pragma unroll
  for (int i=0;i<16;i++) {
    int r = i*4 + r0;
    out[(size_t)(n0+r)*K + k0 + c] = lds[c][r];
  }
}

// ---------------------------------------------------------------- head token
__global__ __launch_bounds__(256) void ht_kernel(
    const u16* __restrict__ xc, const void* __restrict__ xr,
    const u16* __restrict__ htw, const u16* __restrict__ htb,
    const u16* __restrict__ lng, const u16* __restrict__ lnb,
    const u16* __restrict__ pos, u16* __restrict__ ht, const int* __restrict__ flag)
{
  const int b = blockIdx.x, half = blockIdx.y;
  const int tid = threadIdx.x;
  __shared__ float part[4][384];
  __shared__ float msh[384];
  const int f = *flag;
  const u16* x = f ? (const u16*)xr : xc;

  const u16* xb = x + (size_t)b*NTOK*CDIM + half*384;
  if (tid < 192) {
    const int s = tid % 48, rg = tid / 48;
    float a[8] = {0.f,0.f,0.f,0.f,0.f,0.f,0.f,0.f};
    for (int n = rg; n < NTOK; n += 4) {
      u16x8 v = *(const u16x8*)&xb[(size_t)n*CDIM + s*8];
      #pragma unroll
      for (int e=0;e<8;e++) a[e] += bf2f(v[e]);
    }
    #pragma unroll
    for (int e=0;e<8;e++) part[rg][s*8+e] = a[e];
  }
  __syncthreads();
  for (int i = tid; i < 384; i += 256)
    msh[i] = (part[0][i]+part[1][i]+part[2][i]+part[3][i]) * (1.0f/(float)NTOK);
  __syncthreads();

  const float gam = bf2f(lng[tid & 63]), bet = bf2f(lnb[tid & 63]);
  #pragma unroll
  for (int hh = 0; hh < 6; hh++) {
    const int h = half*6 + hh;
    float v0 = bf2f(htb[tid]), v1 = bf2f(htb[tid+256]), v2 = bf2f(htb[tid+512]);
    const float* mh = &msh[hh*HD];
    for (int d = 0; d < HD; d++) {
      const float md = mh[d];
      const u16* wr = htw + (size_t)d*CDIM;
      v0 += md * bf2f(wr[tid]);
      v1 += md * bf2f(wr[tid+256]);
      v2 += md * bf2f(wr[tid+512]);
    }
    float vv[3] = {v0, v1, v2};
    #pragma unroll
    for (int ch = 0; ch < 3; ch++) {
      int c = ch*256 + tid;
      float mu = wsum64(vv[ch]) * (1.0f/(float)HD);
      float dv = vv[ch] - mu;
      float var = wsum64(dv*dv) * (1.0f/(float)HD);
      float y = dv * rsqrtf(var + 1e-5f) * gam + bet;
      float ge = 0.5f * y * (1.0f + erff(y * 0.70710678118654752f));
      float o = ge + bf2f(pos[h*CDIM + c]);
      ht[((size_t)(b*NH + h))*CDIM + c] = f2bf(o);
    }
  }
}

// ---------------------------------------------------------------- GEMM
// 128x128 tile, BK=32, 4 waves (2x2, 64x64 each). NEW vs R11:
//  - ring-4 buffers, depth-3 prefetch, steady vmcnt(12): ~3 iters (~1200cy)
//    of latency cover so stage(kt) is long-landed at its vmcnt.
//    WAR: STAGE(kt+3) overwrites buf((kt-1)&3); reads of that buf completed
//    before barrier2(kt-1), which precedes this STAGE in program order.
//  - MODE 0 epilogue: plain contiguous write qout[r*2304+c] (no scatter/div).
// Both-sides XOR seg swizzle + m204 bijective XCD remap (R11-proven).
template<int MODE>
__global__ __launch_bounds__(256, 2) void gemm_kernel(
    const u16* __restrict__ A0c, const void* __restrict__ A0r,
    const u16* __restrict__ A1,
    const u16* __restrict__ Bt, const u16* __restrict__ bias,
    u16* __restrict__ qout,
    void* __restrict__ outv, float* __restrict__ csb, const int* __restrict__ flag)
{
  const int tid = threadIdx.x;
  const int lane = tid & 63;
  const int w = tid >> 6;
  const int wm = w >> 1, wn = w & 1;
  const int lr = lane & 15, kg = lane >> 4;

  const int NT = gridDim.x;
  const int nwg = NT * gridDim.y;
  const int orig = blockIdx.y * NT + blockIdx.x;
  const int xcd = orig & 7, sIdx = orig >> 3;
  const int q = nwg >> 3, r = nwg & 7;
  const int wg = ((xcd < r) ? xcd*(q+1) : r*(q+1) + (xcd-r)*q) + sIdx;
  const int tm = wg / NT, tn = wg - tm*NT;

  __shared__ __align__(16) u16 As[4][4096];   // [buf][row*32 + seg*8 + e]
  __shared__ __align__(16) u16 Bs[4][4096];

  const int f = *flag;
  const u16* A0 = (MODE == 0) ? (f ? (const u16*)A0r : A0c) : A0c;
  const int NBC = (MODE == 0) ? NQKV : CDIM;

  f32x4 acc[4][4];
  #pragma unroll
  for (int i=0;i<4;i++)
    #pragma unroll
    for (int j=0;j<4;j++) acc[i][j] = (f32x4){0.f,0.f,0.f,0.f};

  const u16* garow[2];
  const u16* gbrow[2];
  #pragma unroll
  for (int i=0;i<2;i++){
    int row = (i*4 + w)*16 + (lane >> 2);
    int rr = tm*128 + row; if (rr > GM-1) rr = GM-1;
    if (MODE == 0) {
      int bb = rr / TT; int t = rr - bb*TT;
      garow[i] = (t < NTOK) ? (A0 + (size_t)(bb*NTOK + t)*CDIM)
                            : (A1 + (size_t)(bb*NH + (t - NTOK))*CDIM);
    } else {
      garow[i] = A0 + (size_t)rr*CDIM;
    }
    gbrow[i] = Bt + (size_t)(tn*128 + row)*CDIM;
  }
  const int gseg = (lane & 3) ^ ((lane >> 3) & 3);   // = seg ^ ((row>>1)&3)

#define STAGE(kt_, bf_) do { \
    const int ko_ = (kt_)*32 + gseg*8; \
    gll16(garow[0] + ko_, (void*)&As[bf_][(0*4+w)*512]); \
    gll16(garow[1] + ko_, (void*)&As[bf_][(1*4+w)*512]); \
    gll16(gbrow[0] + ko_, (void*)&Bs[bf_][(0*4+w)*512]); \
    gll16(gbrow[1] + ko_, (void*)&Bs[bf_][(1*4+w)*512]); \
  } while(0)

  STAGE(0, 0);
  STAGE(1, 1);
  STAGE(2, 2);

  const int spA = kg ^ ((lr >> 1) & 3);   // read-side swizzled segment

  #pragma unroll
  for (int kt = 0; kt < 24; kt++) {
    const int cb = kt & 3;
    if (kt < 21) {
      STAGE(kt+3, (kt+3)&3);
      asm volatile("s_waitcnt vmcnt(12)" ::: "memory");   // stage kt drained
    } else if (kt == 21) {
      asm volatile("s_waitcnt vmcnt(8)" ::: "memory");
    } else if (kt == 22) {
      asm volatile("s_waitcnt vmcnt(4)" ::: "memory");
    } else {
      asm volatile("s_waitcnt vmcnt(0)" ::: "memory");
    }
    __builtin_amdgcn_s_barrier();                        // stage(kt) visible to all

    bf16x8 av[4], bv[4];
    #pragma unroll
    for (int mi=0; mi<4; mi++)
      av[mi] = *(const bf16x8*)&As[cb][(wm*64+mi*16+lr)*32 + spA*8];
    #pragma unroll
    for (int ni=0; ni<4; ni++)
      bv[ni] = *(const bf16x8*)&Bs[cb][(wn*64+ni*16+lr)*32 + spA*8];
    #pragma unroll
    for (int mi=0; mi<4; mi++)
      #pragma unroll
      for (int ni=0; ni<4; ni++)
        acc[mi][ni] = __builtin_amdgcn_mfma_f32_16x16x32_bf16(av[mi], bv[ni], acc[mi][ni], 0,0,0);

    __builtin_amdgcn_s_barrier();                        // WAR guard for buf reuse
  }
#undef STAGE

  #pragma unroll
  for (int mi=0; mi<4; mi++){
    const int rb = tm*128 + wm*64 + mi*16 + kg*4;
    #pragma unroll
    for (int ni=0; ni<4; ni++){
      const int c = tn*128 + wn*64 + ni*16 + lr;
      const float bs = bf2f(bias[c]);
      if (MODE == 0) {
        #pragma unroll
        for (int j=0;j<4;j++){
          int rr = rb + j;
          if (rr < GM) qout[(size_t)rr*NQKV + c] = f2bf(acc[mi][ni][j] + bs);
        }
      } else {
        #pragma unroll
        for (int j=0;j<4;j++){
          int rr = rb + j;
          if (rr < GM) {
            int bb = rr / TT; int t = rr - bb*TT;
            float v = acc[mi][ni][j] + bs;
            if (t >= 1 && t < NTOK) {
              size_t oi = ((size_t)(bb*NTOK + t))*CDIM + c;
              if (f) ((u16*)outv)[oi] = f2bf(v);
              else   ((float*)outv)[oi] = v;
            } else {
              int idx = (t == 0) ? 0 : (t - NTOK + 1);   // 0, 1..12
              csb[((size_t)(bb*13 + idx))*CDIM + c] = v;
            }
          }
        }
      }
    }
  }
  (void)NBC;
}

// ---------------------------------------------------------------- vtrans
// (b,h): v slice of qkvo (rows t, cols 1536+h*64..+63) -> vb (b,h,d,VTP),
// zero-padded t in [TT, VTP). grid (4 t-tiles, BATCH*NH), 256 thr.
__global__ __launch_bounds__(256) void vtrans_kernel(
    const u16* __restrict__ qkvo, u16* __restrict__ vb)
{
  __shared__ u16 lds[64][66];
  const int tt0 = blockIdx.x*64;
  const int bh = blockIdx.y;
  const int b = bh / NH, h = bh - b*NH;
  const int c = threadIdx.x & 63, r0 = threadIdx.x >> 6;
  #pragma unroll
  for (int i=0;i<16;i++) {
    int t = tt0 + i*4 + r0;
    u16 v = 0;
    if (t < TT) v = qkvo[(size_t)(b*TT + t)*NQKV + 1536 + h*64 + c];
    lds[i*4+r0][c] = v;
  }
  __syncthreads();
  #pragma unroll
  for (int i=0;i<16;i++) {
    int d = i*4 + r0;
    int t = tt0 + c;
    if (t < VTP) vb[((size_t)(bh)*HD + d)*VTP + t] = lds[c][d];
  }
}

// ---------------------------------------------------------------- attention
// One wave per (b,h, 16-q-row chunk). q/k read directly from qkvo (row stride
// 2304 — same L2 line count per fragment as the old packed layout); V^T frags
// from vb. Swapped QK^T; softmax via 2 shfl_xor; P bf16 in per-wave subtiled
// LDS. No __syncthreads.
__global__ __launch_bounds__(256) void attn_kernel(
    const u16* __restrict__ qkvo, const u16* __restrict__ vt, u16* __restrict__ ob)
{
  __shared__ __align__(16) u16 P[4][7*16*32];   // 28672 B
  const int tid = threadIdx.x;
  const int lane = tid & 63;
  const int w = tid >> 6;
  const int lr = lane & 15, kg = lane >> 4;

  const int cid = blockIdx.x*4 + w;
  const int bh = cid / 14, ck = cid - bh*14;
  const int b = bh / NH, h = bh - b*NH;
  const int q0 = ck*16;

  const u16* qg  = qkvo + (size_t)(b*TT)*NQKV + h*64;
  const u16* kgp = qg + CDIM;
  const u16* vg  = vt + (size_t)bh*HD*VTP;

  int qrow = q0 + lr; if (qrow > TT-1) qrow = TT-1;
  const bf16x8 qf0 = *(const bf16x8*)&qg[(size_t)qrow*NQKV + kg*8];
  const bf16x8 qf1 = *(const bf16x8*)&qg[(size_t)qrow*NQKV + 32 + kg*8];

  f32x4 sv[14];
  #pragma unroll
  for (int kt = 0; kt < 14; kt++) {
    int krow = kt*16 + lr; if (krow > TT-1) krow = TT-1;
    const u16* kr = kgp + (size_t)krow*NQKV;
    bf16x8 kf0 = *(const bf16x8*)&kr[kg*8];
    bf16x8 kf1 = *(const bf16x8*)&kr[32 + kg*8];
    f32x4 sa = {0.f,0.f,0.f,0.f};
    sa = __builtin_amdgcn_mfma_f32_16x16x32_bf16(kf0, qf0, sa, 0,0,0);
    sa = __builtin_amdgcn_mfma_f32_16x16x32_bf16(kf1, qf1, sa, 0,0,0);
    sv[kt] = sa;
  }

  float m = -3.0e38f;
  #pragma unroll
  for (int kt = 0; kt < 13; kt++)
    #pragma unroll
    for (int j=0;j<4;j++){ sv[kt][j] *= 0.125f; m = fmaxf(m, sv[kt][j]); }
  #pragma unroll
  for (int j=0;j<4;j++){
    sv[13][j] *= 0.125f;
    if (208 + kg*4 + j < TT) m = fmaxf(m, sv[13][j]);
  }
  m = fmaxf(m, __shfl_xor(m, 16, 64));
  m = fmaxf(m, __shfl_xor(m, 32, 64));

  float ssum = 0.f;
  #pragma unroll
  for (int kt = 0; kt < 13; kt++)
    #pragma unroll
    for (int j=0;j<4;j++){ float e = __expf(sv[kt][j] - m); sv[kt][j] = e; ssum += e; }
  #pragma unroll
  for (int j=0;j<4;j++){
    float e = (208 + kg*4 + j < TT) ? __expf(sv[13][j] - m) : 0.f;
    sv[13][j] = e; ssum += e;
  }
  ssum += __shfl_xor(ssum, 16, 64);
  ssum += __shfl_xor(ssum, 32, 64);
  const float inv = 1.0f / ssum;

  u16* Pw = &P[w][0];
  #pragma unroll
  for (int kt = 0; kt < 14; kt++) {
    u16x4 pk;
    #pragma unroll
    for (int j=0;j<4;j++) pk[j] = f2bf(sv[kt][j] * inv);
    *(u16x4*)&Pw[(kt>>1)*512 + lr*32 + (kt&1)*16 + kg*4] = pk;
  }

  f32x4 acc[4];
  #pragma unroll
  for (int dt=0; dt<4; dt++) acc[dt] = (f32x4){0.f,0.f,0.f,0.f};
  #pragma unroll
  for (int ks = 0; ks < 7; ks++) {
    bf16x8 pf = *(const bf16x8*)&Pw[ks*512 + lr*32 + kg*8];
    #pragma unroll
    for (int dt = 0; dt < 4; dt++) {
      bf16x8 vf = *(const bf16x8*)&vg[(dt*16+lr)*VTP + ks*32 + kg*8];
      acc[dt] = __builtin_amdgcn_mfma_f32_16x16x32_bf16(pf, vf, acc[dt], 0,0,0);
    }
  }

  #pragma unroll
  for (int dt = 0; dt < 4; dt++)
    #pragma unroll
    for (int j = 0; j < 4; j++) {
      int tq = q0 + kg*4 + j;
      if (tq < TT)
        ob[((size_t)(b*TT + tq))*CDIM + h*HD + dt*16 + lr] = f2bf(acc[dt][j]);
    }
}

// ---------------------------------------------------------------- final2 (cls row)
__global__ __launch_bounds__(256) void final2_kernel(
    const float* __restrict__ csb, void* __restrict__ outv, const int* __restrict__ flag)
{
  const int f = *flag;
  int i = blockIdx.x*256 + threadIdx.x;
  if (i >= BATCH*CDIM) return;
  int b = i / CDIM, c = i - b*CDIM;
  const float* p = csb + (size_t)b*13*CDIM + c;
  float s = 0.f;
  #pragma unroll
  for (int j = 1; j <= 12; j++) s += p[(size_t)j*CDIM];
  float v = p[0] + s * (1.0f/12.0f);
  size_t oi = ((size_t)b*NTOK)*CDIM + c;
  if (f) ((u16*)outv)[oi] = f2bf(v);
  else   ((float*)outv)[oi] = v;
}

// ---------------------------------------------------------------- launch
extern "C" void kernel_launch(void* const* d_in, const int* in_sizes, int n_in,
                              void* d_out, int out_size, void* d_ws, size_t ws_size,
                              hipStream_t stream)
{
  char* ws = (char*)d_ws;
  size_t off = 0;
  auto alloc = [&](size_t bytes)->void* {
    void* p = ws + off; off += (bytes + 255) & ~(size_t)255; return p;
  };

  int* flag = (int*)alloc(256);

  u16* cin[10];
  for (int i = 0; i < 10; i++) cin[i] = (u16*)alloc((size_t)in_sizes[i]*2);

  u16* qkvT  = (u16*)alloc((size_t)3*CDIM*CDIM*2);        // 2304 x 768
  u16* projT = (u16*)alloc((size_t)CDIM*CDIM*2);          // 768 x 768
  u16* htb_  = (u16*)alloc((size_t)BATCH*NH*CDIM*2);      // (B*H) x 768
  u16* qkvo  = (u16*)alloc((size_t)GM*NQKV*2);            // (B*T) x 2304
  u16* vb    = (u16*)alloc((size_t)BATCH*NH*HD*VTP*2);    // (B,H,HD,VTP)
  float* csb = (float*)alloc((size_t)BATCH*13*CDIM*4);    // cls side buffer
  // ao aliases the x-copy region (cin[0]+cin[1] = 22.8MB >= 20.6MB):
  // x is dead after gemm<0>; cin[1] (qkv_w slot) is never used.
  u16* ao    = cin[0];

  detect_kernel<<<1, 64, 0, stream>>>((const u16*)d_in[0], flag);

  CA ca;
  for (int i = 0; i < 10; i++) { ca.in[i] = d_in[i]; ca.out[i] = cin[i]; ca.n[i] = in_sizes[i]; }
  convert_all_kernel<<<dim3(256, 10), 256, 0, stream>>>(ca, flag);

  transpose_kernel<<<dim3(3*CDIM/64, CDIM/64), 256, 0, stream>>>(d_in[1], qkvT, CDIM, 3*CDIM, flag);
  transpose_kernel<<<dim3(CDIM/64,   CDIM/64), 256, 0, stream>>>(d_in[3], projT, CDIM, CDIM, flag);
  ht_kernel<<<dim3(BATCH, 2), 256, 0, stream>>>(cin[0], d_in[0], cin[5], cin[6], cin[7], cin[8], cin[9], htb_, flag);
  gemm_kernel<0><<<dim3(NQKV/128, (GM+127)/128), 256, 0, stream>>>(
      cin[0], d_in[0], htb_, qkvT, cin[2], qkvo, nullptr, nullptr, flag);
  vtrans_kernel<<<dim3(4, BATCH*NH), 256, 0, stream>>>(qkvo, vb);
  attn_kernel<<<(BATCH*NH*14)/4, 256, 0, stream>>>(qkvo, vb, ao);
  gemm_kernel<1><<<dim3(CDIM/128, (GM+127)/128), 256, 0, stream>>>(
      ao, nullptr, nullptr, projT, cin[4], nullptr, d_out, csb, flag);
  final2_kernel<<<(BATCH*CDIM+255)/256, 256, 0, stream>>>(csb, d_out, flag);
}

// Round 15
// 265.618 us; speedup vs baseline: 1.2229x; 1.0384x over previous
//
#include <hip/hip_runtime.h>
#include <cstdint>
#include <cstddef>

typedef unsigned short u16;
typedef __attribute__((ext_vector_type(8))) __bf16 bf16x8;
typedef __attribute__((ext_vector_type(4))) unsigned short u16x4;
typedef __attribute__((ext_vector_type(8))) unsigned short u16x8;
typedef __attribute__((ext_vector_type(4))) float f32x4;

#define NTOK 197
#define TT   209
#define CDIM 768
#define NH   12
#define HD   64
#define BATCH 64
#define GM (BATCH*TT)   // 13376
#define VTP 224         // padded T stride for transposed V
#define NQKV 2304

__device__ __forceinline__ float bf2f(u16 u){ return __uint_as_float(((unsigned)u)<<16); }
__device__ __forceinline__ u16 f2bf(float f){
  unsigned x = __float_as_uint(f);
  return (u16)((x + 0x7FFFu + ((x>>16)&1u)) >> 16);   // RNE; inputs finite
}

__device__ __forceinline__ void gll16(const void* g, void* l){
  __builtin_amdgcn_global_load_lds((const __attribute__((address_space(1))) void*)g,
                                   (__attribute__((address_space(3))) void*)l,
                                   16, 0, 0);
}

__device__ __forceinline__ float wsum64(float v){
  #pragma unroll
  for (int o = 32; o > 0; o >>= 1) v += __shfl_xor(v, o, 64);
  return v;
}

// ---------------------------------------------------------------- dtype detect
__global__ __launch_bounds__(64) void detect_kernel(const u16* __restrict__ x, int* flag){
  const int lane = threadIdx.x;
  float mx = 0.f;
  #pragma unroll
  for (int i = 0; i < 16; i++) {
    float v = fabsf(bf2f(x[i*64 + lane]));
    if (!(v < 1e30f)) v = 1e30f;
    mx = fmaxf(mx, v);
  }
  #pragma unroll
  for (int o = 32; o; o >>= 1) mx = fmaxf(mx, __shfl_xor(mx, o, 64));
  if (lane == 0) *flag = (mx < 1e5f) ? 1 : 0;   // 1 = device buffers are bf16
}

// ---------------------------------------------------------------- fused convert
struct CA { const void* in[10]; void* out[10]; int n[10]; };
__global__ __launch_bounds__(256) void convert_all_kernel(CA a, const int* __restrict__ flag){
  const int seg = blockIdx.y;
  if (seg == 1 || seg == 3) return;
  const int f = *flag;
  if (seg == 0 && f) return;
  const int n = a.n[seg];
  const int n4 = n >> 2;
  u16* out = (u16*)a.out[seg];
  if (f) {
    const u16x4* in = (const u16x4*)a.in[seg];
    for (int i = blockIdx.x*256 + threadIdx.x; i < n4; i += gridDim.x*256)
      ((u16x4*)out)[i] = in[i];
  } else {
    const f32x4* in = (const f32x4*)a.in[seg];
    for (int i = blockIdx.x*256 + threadIdx.x; i < n4; i += gridDim.x*256){
      f32x4 v = in[i];
      u16x4 o;
      #pragma unroll
      for (int j=0;j<4;j++) o[j] = f2bf(v[j]);
      ((u16x4*)out)[i] = o;
    }
  }
  if (blockIdx.x == 0 && (int)threadIdx.x < (n & 3)) {
    int i = (n4 << 2) + threadIdx.x;
    out[i] = f ? ((const u16*)a.in[seg])[i] : f2bf(((const float*)a.in[seg])[i]);
  }
}

// ---------------------------------------------------------------- fused transpose (+convert)
// bid < 432: qkv_w (768x2304) tile; else proj_w (768x768) tile.
__global__ __launch_bounds__(256) void transpose2_kernel(
    const void* __restrict__ w1, const void* __restrict__ w2,
    u16* __restrict__ o1, u16* __restrict__ o2, const int* __restrict__ flag)
{
  __shared__ u16 lds[64][66];
  const int f = *flag;
  int bid = blockIdx.x;
  const void* in; u16* out; int K, N, tx, ty;
  if (bid < 432) { in = w1; out = o1; K = CDIM; N = NQKV; tx = bid % 36; ty = bid / 36; }
  else { bid -= 432; in = w2; out = o2; K = CDIM; N = CDIM; tx = bid % 12; ty = bid / 12; }
  const int n0 = tx*64, k0 = ty*64;
  const int c = threadIdx.x & 63, r0 = threadIdx.x >> 6;
  #pragma unroll
  for (int i=0;i<16;i++) {
    int r = i*4 + r0;
    size_t idx = (size_t)(k0+r)*N + n0 + c;
    lds[r][c] = f ? ((const u16*)in)[idx] : f2bf(((const float*)in)[idx]);
  }
  __syncthreads();
  #pragma unroll
  for (int i=0;i<16;i++) {
    int r = i*4 + r0;
    out[(size_t)(n0+r)*K + k0 + c] = lds[c][r];
  }
}

// ---------------------------------------------------------------- head token
__global__ __launch_bounds__(256) void ht_kernel(
    const u16* __restrict__ xc, const void* __restrict__ xr,
    const u16* __restrict__ htw, const u16* __restrict__ htb,
    const u16* __restrict__ lng, const u16* __restrict__ lnb,
    const u16* __restrict__ pos, u16* __restrict__ ht, const int* __restrict__ flag)
{
  const int b = blockIdx.x, half = blockIdx.y;
  const int tid = threadIdx.x;
  __shared__ float part[4][384];
  __shared__ float msh[384];
  const int f = *flag;
  const u16* x = f ? (const u16*)xr : xc;

  const u16* xb = x + (size_t)b*NTOK*CDIM + half*384;
  if (tid < 192) {
    const int s = tid % 48, rg = tid / 48;
    float a[8] = {0.f,0.f,0.f,0.f,0.f,0.f,0.f,0.f};
    for (int n = rg; n < NTOK; n += 4) {
      u16x8 v = *(const u16x8*)&xb[(size_t)n*CDIM + s*8];
      #pragma unroll
      for (int e=0;e<8;e++) a[e] += bf2f(v[e]);
    }
    #pragma unroll
    for (int e=0;e<8;e++) part[rg][s*8+e] = a[e];
  }
  __syncthreads();
  for (int i = tid; i < 384; i += 256)
    msh[i] = (part[0][i]+part[1][i]+part[2][i]+part[3][i]) * (1.0f/(float)NTOK);
  __syncthreads();

  const float gam = bf2f(lng[tid & 63]), bet = bf2f(lnb[tid & 63]);
  #pragma unroll
  for (int hh = 0; hh < 6; hh++) {
    const int h = half*6 + hh;
    float v0 = bf2f(htb[tid]), v1 = bf2f(htb[tid+256]), v2 = bf2f(htb[tid+512]);
    const float* mh = &msh[hh*HD];
    for (int d = 0; d < HD; d++) {
      const float md = mh[d];
      const u16* wr = htw + (size_t)d*CDIM;
      v0 += md * bf2f(wr[tid]);
      v1 += md * bf2f(wr[tid+256]);
      v2 += md * bf2f(wr[tid+512]);
    }
    float vv[3] = {v0, v1, v2};
    #pragma unroll
    for (int ch = 0; ch < 3; ch++) {
      int c = ch*256 + tid;
      float mu = wsum64(vv[ch]) * (1.0f/(float)HD);
      float dv = vv[ch] - mu;
      float var = wsum64(dv*dv) * (1.0f/(float)HD);
      float y = dv * rsqrtf(var + 1e-5f) * gam + bet;
      float ge = 0.5f * y * (1.0f + erff(y * 0.70710678118654752f));
      float o = ge + bf2f(pos[h*CDIM + c]);
      ht[((size_t)(b*NH + h))*CDIM + c] = f2bf(o);
    }
  }
}

// ---------------------------------------------------------------- GEMM
// 128x128 tile, BK=32, 4 waves (2x2). NEW vs R14: ring-5 buffers (80KB),
// depth-3 prefetch, SINGLE barrier/iter. Safety:
//  RAW: own vmcnt(12) (3 stages x 4 loads in flight) + barrier => all waves'
//       stage(kt) landed before any ds_read of buf kt%5.
//  WAR: STAGE(kt+3) writes buf (kt+3)%5 = (kt-2)%5, last read at iter kt-2;
//       the issuing wave crossed barrier #kt, which all waves reach only
//       after finishing iter kt-1 reads => write-to-last-read distance 2.
// MODE 0 epilogue: contiguous qkvo write. XOR seg swizzle + m204 XCD remap.
template<int MODE>
__global__ __launch_bounds__(256, 2) void gemm_kernel(
    const u16* __restrict__ A0c, const void* __restrict__ A0r,
    const u16* __restrict__ A1,
    const u16* __restrict__ Bt, const u16* __restrict__ bias,
    u16* __restrict__ qout,
    void* __restrict__ outv, float* __restrict__ csb, const int* __restrict__ flag)
{
  const int tid = threadIdx.x;
  const int lane = tid & 63;
  const int w = tid >> 6;
  const int wm = w >> 1, wn = w & 1;
  const int lr = lane & 15, kg = lane >> 4;

  const int NT = gridDim.x;
  const int nwg = NT * gridDim.y;
  const int orig = blockIdx.y * NT + blockIdx.x;
  const int xcd = orig & 7, sIdx = orig >> 3;
  const int q = nwg >> 3, r = nwg & 7;
  const int wg = ((xcd < r) ? xcd*(q+1) : r*(q+1) + (xcd-r)*q) + sIdx;
  const int tm = wg / NT, tn = wg - tm*NT;

  __shared__ __align__(16) u16 As[5][4096];   // [buf][row*32 + seg*8 + e]
  __shared__ __align__(16) u16 Bs[5][4096];

  const int f = *flag;
  const u16* A0 = (MODE == 0) ? (f ? (const u16*)A0r : A0c) : A0c;

  f32x4 acc[4][4];
  #pragma unroll
  for (int i=0;i<4;i++)
    #pragma unroll
    for (int j=0;j<4;j++) acc[i][j] = (f32x4){0.f,0.f,0.f,0.f};

  const u16* garow[2];
  const u16* gbrow[2];
  #pragma unroll
  for (int i=0;i<2;i++){
    int row = (i*4 + w)*16 + (lane >> 2);
    int rr = tm*128 + row; if (rr > GM-1) rr = GM-1;
    if (MODE == 0) {
      int bb = rr / TT; int t = rr - bb*TT;
      garow[i] = (t < NTOK) ? (A0 + (size_t)(bb*NTOK + t)*CDIM)
                            : (A1 + (size_t)(bb*NH + (t - NTOK))*CDIM);
    } else {
      garow[i] = A0 + (size_t)rr*CDIM;
    }
    gbrow[i] = Bt + (size_t)(tn*128 + row)*CDIM;
  }
  const int gseg = (lane & 3) ^ ((lane >> 3) & 3);   // = seg ^ ((row>>1)&3)

#define STAGE(kt_, bf_) do { \
    const int ko_ = (kt_)*32 + gseg*8; \
    gll16(garow[0] + ko_, (void*)&As[bf_][(0*4+w)*512]); \
    gll16(garow[1] + ko_, (void*)&As[bf_][(1*4+w)*512]); \
    gll16(gbrow[0] + ko_, (void*)&Bs[bf_][(0*4+w)*512]); \
    gll16(gbrow[1] + ko_, (void*)&Bs[bf_][(1*4+w)*512]); \
  } while(0)

  STAGE(0, 0);
  STAGE(1, 1);
  STAGE(2, 2);

  const int spA = kg ^ ((lr >> 1) & 3);   // read-side swizzled segment

  #pragma unroll
  for (int kt = 0; kt < 24; kt++) {
    const int cb = kt % 5;
    if (kt < 21) {
      STAGE(kt+3, (kt+3)%5);
      asm volatile("s_waitcnt vmcnt(12)" ::: "memory");   // stage kt drained
    } else if (kt == 21) {
      asm volatile("s_waitcnt vmcnt(8)" ::: "memory");
    } else if (kt == 22) {
      asm volatile("s_waitcnt vmcnt(4)" ::: "memory");
    } else {
      asm volatile("s_waitcnt vmcnt(0)" ::: "memory");
    }
    __builtin_amdgcn_s_barrier();     // single barrier/iter (ring-5 WAR proof)

    bf16x8 av[4], bv[4];
    #pragma unroll
    for (int mi=0; mi<4; mi++)
      av[mi] = *(const bf16x8*)&As[cb][(wm*64+mi*16+lr)*32 + spA*8];
    #pragma unroll
    for (int ni=0; ni<4; ni++)
      bv[ni] = *(const bf16x8*)&Bs[cb][(wn*64+ni*16+lr)*32 + spA*8];
    #pragma unroll
    for (int mi=0; mi<4; mi++)
      #pragma unroll
      for (int ni=0; ni<4; ni++)
        acc[mi][ni] = __builtin_amdgcn_mfma_f32_16x16x32_bf16(av[mi], bv[ni], acc[mi][ni], 0,0,0);
  }
#undef STAGE

  #pragma unroll
  for (int mi=0; mi<4; mi++){
    const int rb = tm*128 + wm*64 + mi*16 + kg*4;
    #pragma unroll
    for (int ni=0; ni<4; ni++){
      const int c = tn*128 + wn*64 + ni*16 + lr;
      const float bs = bf2f(bias[c]);
      if (MODE == 0) {
        #pragma unroll
        for (int j=0;j<4;j++){
          int rr = rb + j;
          if (rr < GM) qout[(size_t)rr*NQKV + c] = f2bf(acc[mi][ni][j] + bs);
        }
      } else {
        #pragma unroll
        for (int j=0;j<4;j++){
          int rr = rb + j;
          if (rr < GM) {
            int bb = rr / TT; int t = rr - bb*TT;
            float v = acc[mi][ni][j] + bs;
            if (t >= 1 && t < NTOK) {
              size_t oi = ((size_t)(bb*NTOK + t))*CDIM + c;
              if (f) ((u16*)outv)[oi] = f2bf(v);
              else   ((float*)outv)[oi] = v;
            } else {
              int idx = (t == 0) ? 0 : (t - NTOK + 1);   // 0, 1..12
              csb[((size_t)(bb*13 + idx))*CDIM + c] = v;
            }
          }
        }
      }
    }
  }
}

// ---------------------------------------------------------------- vtrans
__global__ __launch_bounds__(256) void vtrans_kernel(
    const u16* __restrict__ qkvo, u16* __restrict__ vb)
{
  __shared__ u16 lds[64][66];
  const int tt0 = blockIdx.x*64;
  const int bh = blockIdx.y;
  const int b = bh / NH, h = bh - b*NH;
  const int c = threadIdx.x & 63, r0 = threadIdx.x >> 6;
  #pragma unroll
  for (int i=0;i<16;i++) {
    int t = tt0 + i*4 + r0;
    u16 v = 0;
    if (t < TT) v = qkvo[(size_t)(b*TT + t)*NQKV + 1536 + h*64 + c];
    lds[i*4+r0][c] = v;
  }
  __syncthreads();
  #pragma unroll
  for (int i=0;i<16;i++) {
    int d = i*4 + r0;
    int t = tt0 + c;
    if (t < VTP) vb[((size_t)(bh)*HD + d)*VTP + t] = lds[c][d];
  }
}

// ---------------------------------------------------------------- attention
__global__ __launch_bounds__(256) void attn_kernel(
    const u16* __restrict__ qkvo, const u16* __restrict__ vt, u16* __restrict__ ob)
{
  __shared__ __align__(16) u16 P[4][7*16*32];   // 28672 B
  const int tid = threadIdx.x;
  const int lane = tid & 63;
  const int w = tid >> 6;
  const int lr = lane & 15, kg = lane >> 4;

  const int cid = blockIdx.x*4 + w;
  const int bh = cid / 14, ck = cid - bh*14;
  const int b = bh / NH, h = bh - b*NH;
  const int q0 = ck*16;

  const u16* qg  = qkvo + (size_t)(b*TT)*NQKV + h*64;
  const u16* kgp = qg + CDIM;
  const u16* vg  = vt + (size_t)bh*HD*VTP;

  int qrow = q0 + lr; if (qrow > TT-1) qrow = TT-1;
  const bf16x8 qf0 = *(const bf16x8*)&qg[(size_t)qrow*NQKV + kg*8];
  const bf16x8 qf1 = *(const bf16x8*)&qg[(size_t)qrow*NQKV + 32 + kg*8];

  f32x4 sv[14];
  #pragma unroll
  for (int kt = 0; kt < 14; kt++) {
    int krow = kt*16 + lr; if (krow > TT-1) krow = TT-1;
    const u16* kr = kgp + (size_t)krow*NQKV;
    bf16x8 kf0 = *(const bf16x8*)&kr[kg*8];
    bf16x8 kf1 = *(const bf16x8*)&kr[32 + kg*8];
    f32x4 sa = {0.f,0.f,0.f,0.f};
    sa = __builtin_amdgcn_mfma_f32_16x16x32_bf16(kf0, qf0, sa, 0,0,0);
    sa = __builtin_amdgcn_mfma_f32_16x16x32_bf16(kf1, qf1, sa, 0,0,0);
    sv[kt] = sa;
  }

  float m = -3.0e38f;
  #pragma unroll
  for (int kt = 0; kt < 13; kt++)
    #pragma unroll
    for (int j=0;j<4;j++){ sv[kt][j] *= 0.125f; m = fmaxf(m, sv[kt][j]); }
  #pragma unroll
  for (int j=0;j<4;j++){
    sv[13][j] *= 0.125f;
    if (208 + kg*4 + j < TT) m = fmaxf(m, sv[13][j]);
  }
  m = fmaxf(m, __shfl_xor(m, 16, 64));
  m = fmaxf(m, __shfl_xor(m, 32, 64));

  float ssum = 0.f;
  #pragma unroll
  for (int kt = 0; kt < 13; kt++)
    #pragma unroll
    for (int j=0;j<4;j++){ float e = __expf(sv[kt][j] - m); sv[kt][j] = e; ssum += e; }
  #pragma unroll
  for (int j=0;j<4;j++){
    float e = (208 + kg*4 + j < TT) ? __expf(sv[13][j] - m) : 0.f;
    sv[13][j] = e; ssum += e;
  }
  ssum += __shfl_xor(ssum, 16, 64);
  ssum += __shfl_xor(ssum, 32, 64);
  const float inv = 1.0f / ssum;

  u16* Pw = &P[w][0];
  #pragma unroll
  for (int kt = 0; kt < 14; kt++) {
    u16x4 pk;
    #pragma unroll
    for (int j=0;j<4;j++) pk[j] = f2bf(sv[kt][j] * inv);
    *(u16x4*)&Pw[(kt>>1)*512 + lr*32 + (kt&1)*16 + kg*4] = pk;
  }

  f32x4 acc[4];
  #pragma unroll
  for (int dt=0; dt<4; dt++) acc[dt] = (f32x4){0.f,0.f,0.f,0.f};
  #pragma unroll
  for (int ks = 0; ks < 7; ks++) {
    bf16x8 pf = *(const bf16x8*)&Pw[ks*512 + lr*32 + kg*8];
    #pragma unroll
    for (int dt = 0; dt < 4; dt++) {
      bf16x8 vf = *(const bf16x8*)&vg[(dt*16+lr)*VTP + ks*32 + kg*8];
      acc[dt] = __builtin_amdgcn_mfma_f32_16x16x32_bf16(pf, vf, acc[dt], 0,0,0);
    }
  }

  #pragma unroll
  for (int dt = 0; dt < 4; dt++)
    #pragma unroll
    for (int j = 0; j < 4; j++) {
      int tq = q0 + kg*4 + j;
      if (tq < TT)
        ob[((size_t)(b*TT + tq))*CDIM + h*HD + dt*16 + lr] = f2bf(acc[dt][j]);
    }
}

// ---------------------------------------------------------------- final2 (cls row)
__global__ __launch_bounds__(256) void final2_kernel(
    const float* __restrict__ csb, void* __restrict__ outv, const int* __restrict__ flag)
{
  const int f = *flag;
  int i = blockIdx.x*256 + threadIdx.x;
  if (i >= BATCH*CDIM) return;
  int b = i / CDIM, c = i - b*CDIM;
  const float* p = csb + (size_t)b*13*CDIM + c;
  float s = 0.f;
  #pragma unroll
  for (int j = 1; j <= 12; j++) s += p[(size_t)j*CDIM];
  float v = p[0] + s * (1.0f/12.0f);
  size_t oi = ((size_t)b*NTOK)*CDIM + c;
  if (f) ((u16*)outv)[oi] = f2bf(v);
  else   ((float*)outv)[oi] = v;
}

// ---------------------------------------------------------------- launch
extern "C" void kernel_launch(void* const* d_in, const int* in_sizes, int n_in,
                              void* d_out, int out_size, void* d_ws, size_t ws_size,
                              hipStream_t stream)
{
  char* ws = (char*)d_ws;
  size_t off = 0;
  auto alloc = [&](size_t bytes)->void* {
    void* p = ws + off; off += (bytes + 255) & ~(size_t)255; return p;
  };

  int* flag = (int*)alloc(256);

  u16* cin[10];
  for (int i = 0; i < 10; i++) cin[i] = (u16*)alloc((size_t)in_sizes[i]*2);

  u16* qkvT  = (u16*)alloc((size_t)3*CDIM*CDIM*2);        // 2304 x 768
  u16* projT = (u16*)alloc((size_t)CDIM*CDIM*2);          // 768 x 768
  u16* htb_  = (u16*)alloc((size_t)BATCH*NH*CDIM*2);      // (B*H) x 768
  u16* qkvo  = (u16*)alloc((size_t)GM*NQKV*2);            // (B*T) x 2304
  u16* vb    = (u16*)alloc((size_t)BATCH*NH*HD*VTP*2);    // (B,H,HD,VTP)
  float* csb = (float*)alloc((size_t)BATCH*13*CDIM*4);    // cls side buffer
  u16* ao    = cin[0];   // alias: x dead after gemm<0>; cin[1] never used

  detect_kernel<<<1, 64, 0, stream>>>((const u16*)d_in[0], flag);

  CA ca;
  for (int i = 0; i < 10; i++) { ca.in[i] = d_in[i]; ca.out[i] = cin[i]; ca.n[i] = in_sizes[i]; }
  convert_all_kernel<<<dim3(256, 10), 256, 0, stream>>>(ca, flag);

  transpose2_kernel<<<576, 256, 0, stream>>>(d_in[1], d_in[3], qkvT, projT, flag);
  ht_kernel<<<dim3(BATCH, 2), 256, 0, stream>>>(cin[0], d_in[0], cin[5], cin[6], cin[7], cin[8], cin[9], htb_, flag);
  gemm_kernel<0><<<dim3(NQKV/128, (GM+127)/128), 256, 0, stream>>>(
      cin[0], d_in[0], htb_, qkvT, cin[2], qkvo, nullptr, nullptr, flag);
  vtrans_kernel<<<dim3(4, BATCH*NH), 256, 0, stream>>>(qkvo, vb);
  attn_kernel<<<(BATCH*NH*14)/4, 256, 0, stream>>>(qkvo, vb, ao);
  gemm_kernel<1><<<dim3(CDIM/128, (GM+127)/128), 256, 0, stream>>>(
      ao, nullptr, nullptr, projT, cin[4], nullptr, d_out, csb, flag);
  final2_kernel<<<(BATCH*CDIM+255)/256, 256, 0, stream>>>(csb, d_out, flag);
}